// Round 8
// baseline (217.102 us; speedup 1.0000x reference)
//
#include <hip/hip_runtime.h>
#include <math.h>

#define NN 8192
#define EE 32768
#define WN 2560
#define HID_STRIDE 72            // sh_hidb row stride (bf16)

typedef unsigned short u16;
typedef unsigned int u32;
typedef short short8 __attribute__((ext_vector_type(8)));   // 8 bf16 (MFMA A/B frag)
typedef float f32x4 __attribute__((ext_vector_type(4)));    // MFMA C/D frag

__device__ __forceinline__ u16 f2b(float f) {               // fp32 -> bf16 RNE
    u32 x = __float_as_uint(f);
    return (u16)((x + 0x7fffu + ((x >> 16) & 1u)) >> 16);
}

// ---------------------------------------------------------------------------
// prep: zero agg+cnt (663,552 floats) across 256 blocks; blocks 0..39 also
// transpose W2 [64][2560] fp32 -> W2T [2560][64] bf16 (k contiguous).
// ---------------------------------------------------------------------------
__global__ __launch_bounds__(256) void prep(const float* __restrict__ W2,
                                            u16* __restrict__ W2T,
                                            float* __restrict__ zbase) {
    const int t = threadIdx.x, b = blockIdx.x;
    const float4 z4 = {0.f, 0.f, 0.f, 0.f};
    #pragma unroll
    for (int k = 0; k < 3; ++k) {
        int i = b * 768 + k * 256 + t;              // float4 index
        if (i < 165888) ((float4*)zbase)[i] = z4;   // 165888*4 = 663552 floats
    }
    if (b < 40) {
        __shared__ float tile[64][65];
        const int c0 = b << 6;
        const int tl = t & 63, th = t >> 6;
        #pragma unroll
        for (int r = 0; r < 16; ++r) {
            int kk = (r << 2) + th;
            tile[kk][tl] = W2[kk * WN + c0 + tl];
        }
        __syncthreads();
        #pragma unroll
        for (int r = 0; r < 16; ++r) {
            int c = (r << 2) + th;
            W2T[(size_t)(c0 + c) * 64 + tl] = f2b(tile[tl][c]);
        }
    }
}

// ---------------------------------------------------------------------------
// Edge kernel: 1024 WGs x 256 threads (4 waves), 32 edges per WG.
// Phase B is split into 5 region phases; each phase keeps ONLY its own
// accumulator in registers and flushes partial sums into persistent LDS
// tiles (outS/outV) via ds_add_f32 when the region completes. No barriers
// in phase B; one barrier before the final global-atomic scatter.
// Worst-phase register live set ~100 <= 128 -> 4 WG/CU without spill.
// ---------------------------------------------------------------------------
__global__ __launch_bounds__(256, 4) void edge_kernel(
    const float* __restrict__ h, const float* __restrict__ pos, const int* __restrict__ ei,
    const float* __restrict__ means, const float* __restrict__ betas,
    const float* __restrict__ W1, const float* __restrict__ b1,
    const u16* __restrict__ W2T, const float* __restrict__ b2,
    float* __restrict__ agg, float* __restrict__ cnt)
{
    // phase A coefficient arrays (read-only during phase B):
    //   sh_ss[32][33] @0 (4224) | sh_dot[32][17] @4224 (2176) |
    //   sh_v[32][68] @6400 (8704) | sh_cross[32][68] @15104 (8704) |
    //   sh_hidb @23808 (4608)  -> 28416 B
    __shared__ alignas(16) char sbuf[28416];
    float (*sh_ss)[33]    = (float (*)[33])(sbuf);
    float (*sh_dot)[17]   = (float (*)[17])(sbuf + 4224);
    float (*sh_v)[68]     = (float (*)[68])(sbuf + 6400);
    float (*sh_cross)[68] = (float (*)[68])(sbuf + 15104);
    u16*  sh_hidb         = (u16*)(sbuf + 23808);

    __shared__ float outS[32][33];     // message out_s tile      (4224 B)
    __shared__ float outV[32][49];     // message out_v tile      (6272 B)
    __shared__ float sh_y1[32][3];
    __shared__ float sh_geo[32][2];
    __shared__ int   sh_src[32];
    __shared__ int   sh_dst[32];

    const int t = threadIdx.x;

    // ---- zero the output tiles (published by the phase-A barrier) ----
    {
        float* z = &outS[0][0];
        #pragma unroll
        for (int i = 0; i < 5; ++i) { int p = t + (i<<8); if (p < 1056) z[p] = 0.f; }
        float* z2 = &outV[0][0];
        #pragma unroll
        for (int i = 0; i < 7; ++i) { int p = t + (i<<8); if (p < 1568) z2[p] = 0.f; }
    }

    // ---- A1: per-edge geometry (threads 0..31) ----
    if (t < 32) {
        const int eg = (blockIdx.x << 5) + t;
        const int si = ei[eg];
        const int di = ei[EE + eg];
        float ax = pos[si*3+0], ay = pos[si*3+1], az = pos[si*3+2];
        float bx = pos[di*3+0], by = pos[di*3+1], bz = pos[di*3+2];
        float vx = bx-ax, vy = by-ay, vz = bz-az;
        float d = sqrtf(vx*vx + vy*vy + vz*vz + 1e-12f);
        float invd = 1.7320508075688772f / d;      // sqrt(3)/d
        sh_y1[t][0] = vx*invd; sh_y1[t][1] = vy*invd; sh_y1[t][2] = vz*invd;
        sh_geo[t][0] = expf(-d);                   // ALPHA = 1
        sh_geo[t][1] = (d < 5.0f) ? 0.5f*(cosf(d*0.6283185307179586f) + 1.0f) : 0.0f;
        sh_src[t] = si; sh_dst[t] = di;
    }
    __syncthreads();

    // ---- A2: rbf + hid(bf16) + pre-scaled coefficients (8 threads/edge) ----
    {
        const int e = t >> 3, r = t & 7;
        const float expd = sh_geo[e][0], cut = sh_geo[e][1];
        float rbf[16];
        #pragma unroll
        for (int k = 0; k < 16; ++k) {
            float td = expd - means[k];
            rbf[k] = expf(-betas[k]*td*td) * cut;
        }
        short8 pk;
        #pragma unroll
        for (int jj = 0; jj < 8; ++jj) {
            int j = (r << 3) + jj;
            float a = b1[j];
            #pragma unroll
            for (int k = 0; k < 16; ++k) a += rbf[k] * W1[(k<<6) + j];
            float s = a / (1.0f + expf(-a));        // silu
            pk[jj] = (short)f2b(s);
        }
        *(short8*)&sh_hidb[e*HID_STRIDE + (r<<3)] = pk;

        const int srcn = sh_src[e];
        const float* hrow = h + srcn*80;
        const float y1x = sh_y1[e][0], y1y = sh_y1[e][1], y1z = sh_y1[e][2];
        #pragma unroll
        for (int i = 0; i < 4; ++i) { int u = (r<<2)+i; sh_ss[e][u] = 0.125f * hrow[u]; }
        #pragma unroll
        for (int i = 0; i < 2; ++i) {
            int u = (r<<1)+i;
            float v0 = hrow[32+u*3+0];
            float v1 = hrow[32+u*3+1];
            float v2 = hrow[32+u*3+2];
            sh_v[e][(u<<2)+0] = v0 * 0.14433756729740643f;   // p3 scale folded
            sh_v[e][(u<<2)+1] = v1 * 0.14433756729740643f;
            sh_v[e][(u<<2)+2] = v2 * 0.14433756729740643f;
            sh_dot[e][u] = (v0*y1x + v1*y1y + v2*y1z) * 0.10206207261596574f; // /sqrt3 * p4
            sh_cross[e][(u<<2)+0] = (v1*y1z - v2*y1y) * 0.10206207261596574f; // /sqrt2 * p5
            sh_cross[e][(u<<2)+1] = (v2*y1x - v0*y1z) * 0.10206207261596574f;
            sh_cross[e][(u<<2)+2] = (v0*y1y - v1*y1x) * 0.10206207261596574f;
        }
    }
    __syncthreads();   // publish phase A (+ zeroed out-tiles)

    // ---- A-fragments: hid rows (regs, reused all 160 col tiles) ----
    const int ln = t & 63, wv = t >> 6;
    const int quad = ln >> 4, lm = ln & 15;
    short8 af[2][2];   // [M-tile][K-step]; A[m=lm][k=ks*32+quad*8+j]
    #pragma unroll
    for (int mt = 0; mt < 2; ++mt)
        #pragma unroll
        for (int ks = 0; ks < 2; ++ks)
            af[mt][ks] = *(const short8*)&sh_hidb[(mt*16+lm)*HID_STRIDE + (ks<<5) + (quad<<3)];

    const u16* W2Tq = W2T + (quad<<3);
    // half-chunk cj covers cols [cj*128, cj*128+128); this lane owns cols
    // col = cj*128 + wv*32 + 16i + lm for i=0,1; ew rows e = 16mt+4quad+r.
    auto halfchunk = [&](int cj, f32x4 (&d)[2][2]) {
        #pragma unroll
        for (int i = 0; i < 2; ++i) {
            const int col = (cj<<7) + (wv<<5) + (i<<4) + lm;
            const short8 b0  = *(const short8*)(W2Tq + (size_t)col*64);
            const short8 b1v = *(const short8*)(W2Tq + (size_t)col*64 + 32);
            const float bb = b2[col];
            f32x4 a0 = {0.f,0.f,0.f,0.f}, a1 = {0.f,0.f,0.f,0.f};
            a0 = __builtin_amdgcn_mfma_f32_16x16x32_bf16(af[0][0], b0,  a0, 0,0,0);
            a0 = __builtin_amdgcn_mfma_f32_16x16x32_bf16(af[0][1], b1v, a0, 0,0,0);
            a1 = __builtin_amdgcn_mfma_f32_16x16x32_bf16(af[1][0], b0,  a1, 0,0,0);
            a1 = __builtin_amdgcn_mfma_f32_16x16x32_bf16(af[1][1], b1v, a1, 0,0,0);
            d[i][0] = a0 + bb;    // ew = matmul + b2
            d[i][1] = a1 + bb;
        }
    };

    // ---- phase ss (cj 0..7): j = cj*4+wv, w = lm + 16i ----
    {
        float accS[2][4][2] = {};
        #pragma unroll 1
        for (int cj = 0; cj < 8; ++cj) {
            f32x4 d[2][2];
            halfchunk(cj, d);
            const int j = (cj<<2) + wv;
            #pragma unroll
            for (int mt = 0; mt < 2; ++mt)
                #pragma unroll
                for (int r = 0; r < 4; ++r) {
                    const int e = (mt<<4) + (quad<<2) + r;
                    const float s0 = sh_ss[e][j];
                    accS[mt][r][0] += s0*d[0][mt][r];
                    accS[mt][r][1] += s0*d[1][mt][r];
                }
        }
        #pragma unroll
        for (int mt = 0; mt < 2; ++mt)
            #pragma unroll
            for (int r = 0; r < 4; ++r) {
                const int e = (mt<<4) + (quad<<2) + r;
                atomicAdd(&outS[e][lm],    accS[mt][r][0]);
                atomicAdd(&outS[e][lm+16], accS[mt][r][1]);
            }
    }

    // ---- phase sv (cj 8..11): w = lm, u = (cj-8)*8 + 2wv + i ----
    {
        float accQ[2][4] = {};
        #pragma unroll 1
        for (int cj = 0; cj < 4; ++cj) {
            f32x4 d[2][2];
            halfchunk(cj + 8, d);
            const int ub = (cj<<3) + (wv<<1);
            #pragma unroll
            for (int mt = 0; mt < 2; ++mt)
                #pragma unroll
                for (int r = 0; r < 4; ++r) {
                    const int e = (mt<<4) + (quad<<2) + r;
                    accQ[mt][r] += sh_ss[e][ub]*d[0][mt][r] + sh_ss[e][ub+1]*d[1][mt][r];
                }
        }
        #pragma unroll
        for (int mt = 0; mt < 2; ++mt)
            #pragma unroll
            for (int r = 0; r < 4; ++r) {
                const int e = (mt<<4) + (quad<<2) + r;
                // accQ used 0.125-scaled s; p2 = q2/0.125 * y1 / sqrt(96)
                const float q = accQ[mt][r] * 0.8164965809277261f;
                atomicAdd(&outV[e][3*lm+0], q * sh_y1[e][0]);
                atomicAdd(&outV[e][3*lm+1], q * sh_y1[e][1]);
                atomicAdd(&outV[e][3*lm+2], q * sh_y1[e][2]);
            }
    }

    // ---- phases vs (12..13) / vv0 (14..17) / vv1 (18..19) ----
    {
        float accV[2][4][3] = {};
        #pragma unroll 1
        for (int cj = 0; cj < 2; ++cj) {       // vs: w=lm, u=cj*8+2wv+i
            f32x4 d[2][2];
            halfchunk(cj + 12, d);
            const int ub = (cj<<3) + (wv<<1);
            #pragma unroll
            for (int mt = 0; mt < 2; ++mt)
                #pragma unroll
                for (int r = 0; r < 4; ++r) {
                    const int e = (mt<<4) + (quad<<2) + r;
                    #pragma unroll
                    for (int i = 0; i < 2; ++i) {
                        const float4 vv = *(const float4*)&sh_v[e][(ub+i)<<2];
                        const float ew = d[i][mt][r];
                        accV[mt][r][0] += vv.x * ew;
                        accV[mt][r][1] += vv.y * ew;
                        accV[mt][r][2] += vv.z * ew;
                    }
                }
        }
        {
            float accS[2][4][2] = {};
            #pragma unroll 1
            for (int cj = 0; cj < 4; ++cj) {   // vv0: j=cj*4+wv, w=lm+16i
                f32x4 d[2][2];
                halfchunk(cj + 14, d);
                const int j = (cj<<2) + wv;
                #pragma unroll
                for (int mt = 0; mt < 2; ++mt)
                    #pragma unroll
                    for (int r = 0; r < 4; ++r) {
                        const int e = (mt<<4) + (quad<<2) + r;
                        const float s0 = sh_dot[e][j];
                        accS[mt][r][0] += s0*d[0][mt][r];
                        accS[mt][r][1] += s0*d[1][mt][r];
                    }
            }
            #pragma unroll
            for (int mt = 0; mt < 2; ++mt)
                #pragma unroll
                for (int r = 0; r < 4; ++r) {
                    const int e = (mt<<4) + (quad<<2) + r;
                    atomicAdd(&outS[e][lm],    accS[mt][r][0]);
                    atomicAdd(&outS[e][lm+16], accS[mt][r][1]);
                }
        }
        #pragma unroll 1
        for (int cj = 0; cj < 2; ++cj) {       // vv1: w=lm, u=cj*8+2wv+i
            f32x4 d[2][2];
            halfchunk(cj + 18, d);
            const int ub = (cj<<3) + (wv<<1);
            #pragma unroll
            for (int mt = 0; mt < 2; ++mt)
                #pragma unroll
                for (int r = 0; r < 4; ++r) {
                    const int e = (mt<<4) + (quad<<2) + r;
                    #pragma unroll
                    for (int i = 0; i < 2; ++i) {
                        const float4 cc = *(const float4*)&sh_cross[e][(ub+i)<<2];
                        const float ew = d[i][mt][r];
                        accV[mt][r][0] += cc.x * ew;
                        accV[mt][r][1] += cc.y * ew;
                        accV[mt][r][2] += cc.z * ew;
                    }
                }
        }
        #pragma unroll
        for (int mt = 0; mt < 2; ++mt)
            #pragma unroll
            for (int r = 0; r < 4; ++r) {
                const int e = (mt<<4) + (quad<<2) + r;
                atomicAdd(&outV[e][3*lm+0], accV[mt][r][0]);
                atomicAdd(&outV[e][3*lm+1], accV[mt][r][1]);
                atomicAdd(&outV[e][3*lm+2], accV[mt][r][2]);
            }
    }

    __syncthreads();   // all LDS-atomic flushes complete

    // ---- final: scatter message tiles to agg ----
    #pragma unroll
    for (int k = 0; k < 4; ++k) {
        int p = t + (k<<8); int e = p >> 5; int w = p & 31;
        atomicAdd(&agg[sh_dst[e]*80 + w], outS[e][w]);
    }
    #pragma unroll
    for (int k = 0; k < 6; ++k) {
        int p = t + (k<<8); int e = p/48; int m = p - e*48;
        atomicAdd(&agg[sh_dst[e]*80 + 32 + m], outV[e][m]);
    }
    if (t < 32) atomicAdd(&cnt[sh_dst[t]], 1.0f);
}

// ---------------------------------------------------------------------------
// Node kernel: out = agg/max(cnt,1) + self_interaction + h  (fp32 out).
// Block-uniform split: blocks [0,1024) scalar outputs, [1024,2560) vector.
// ---------------------------------------------------------------------------
__global__ __launch_bounds__(256, 8) void node_kernel(
    const float* __restrict__ h, const float* __restrict__ Wss, const float* __restrict__ Wvv,
    const float* __restrict__ agg, const float* __restrict__ cnt,
    float* __restrict__ out)
{
    const int b = blockIdx.x, t = threadIdx.x;
    if (b < 1024) {                         // scalar: NN*32 outputs
        const int idx = (b<<8) + t;
        const int n = idx >> 5, j = idx & 31;
        const float* hrow = h + n*80;
        float si = 0.f;
        #pragma unroll
        for (int u = 0; u < 32; ++u) si += hrow[u] * Wss[(u<<5)+j];
        float a = agg[n*80+j] / fmaxf(cnt[n], 1.0f);
        out[n*80+j] = a + si*0.17677669529663687f + hrow[j];   // 1/sqrt(32)
    } else {                                // vector: NN*48 outputs
        const int idx = ((b-1024)<<8) + t;
        const int n = idx / 48, m = idx - n*48;
        const int w = m/3, d = m - w*3;
        const float* hrow = h + n*80;
        float si = 0.f;
        #pragma unroll
        for (int u = 0; u < 16; ++u) si += hrow[32+u*3+d] * Wvv[(u<<4)+w];
        float a = agg[n*80+32+m] / fmaxf(cnt[n], 1.0f);
        out[n*80+32+m] = a + si*0.25f + hrow[32+m];            // 1/sqrt(16)
    }
}

extern "C" void kernel_launch(void* const* d_in, const int* in_sizes, int n_in,
                              void* d_out, int out_size, void* d_ws, size_t ws_size,
                              hipStream_t stream) {
    const float* h     = (const float*)d_in[0];
    const float* pos   = (const float*)d_in[1];
    const int*   ei    = (const int*)d_in[2];
    const float* means = (const float*)d_in[3];
    const float* betas = (const float*)d_in[4];
    const float* W1    = (const float*)d_in[5];
    const float* b1    = (const float*)d_in[6];
    const float* W2    = (const float*)d_in[7];
    const float* b2    = (const float*)d_in[8];
    const float* Wss   = (const float*)d_in[9];
    const float* Wvv   = (const float*)d_in[10];

    float* agg = (float*)d_ws;
    float* cnt = agg + (size_t)NN*80;
    u16*   W2T = (u16*)(cnt + NN);          // 2560*64 bf16 = 320 KB

    hipLaunchKernelGGL(prep, dim3(256), dim3(256), 0, stream, W2, W2T, agg);
    hipLaunchKernelGGL(edge_kernel, dim3(EE/32), dim3(256), 0, stream,
                       h, pos, ei, means, betas, W1, b1, W2T, b2, agg, cnt);
    hipLaunchKernelGGL(node_kernel, dim3(2560), dim3(256), 0, stream,
                       h, Wss, Wvv, agg, cnt, (float*)d_out);
}

// Round 9
// 142.102 us; speedup vs baseline: 1.5278x; 1.5278x over previous
//
#include <hip/hip_runtime.h>
#include <math.h>

#define NN 8192
#define EE 32768
#define WN 2560
#define HID_STRIDE 72            // sh_hidb row stride (bf16)

typedef unsigned short u16;
typedef unsigned int u32;
typedef short short8 __attribute__((ext_vector_type(8)));   // 8 bf16 (MFMA A/B frag)
typedef float f32x4 __attribute__((ext_vector_type(4)));    // MFMA C/D frag

__device__ __forceinline__ u16 f2b(float f) {               // fp32 -> bf16 RNE
    u32 x = __float_as_uint(f);
    return (u16)((x + 0x7fffu + ((x >> 16) & 1u)) >> 16);
}

// ---------------------------------------------------------------------------
// prep: zero agg+cnt (663,552 floats) across 256 blocks; blocks 0..39 also
// transpose W2 [64][2560] fp32 -> W2T [2560][64] bf16 (k contiguous).
// ---------------------------------------------------------------------------
__global__ __launch_bounds__(256) void prep(const float* __restrict__ W2,
                                            u16* __restrict__ W2T,
                                            float* __restrict__ zbase) {
    const int t = threadIdx.x, b = blockIdx.x;
    const float4 z4 = {0.f, 0.f, 0.f, 0.f};
    #pragma unroll
    for (int k = 0; k < 3; ++k) {
        int i = b * 768 + k * 256 + t;              // float4 index
        if (i < 165888) ((float4*)zbase)[i] = z4;   // 165888*4 = 663552 floats
    }
    if (b < 40) {
        __shared__ float tile[64][65];
        const int c0 = b << 6;
        const int tl = t & 63, th = t >> 6;
        #pragma unroll
        for (int r = 0; r < 16; ++r) {
            int kk = (r << 2) + th;
            tile[kk][tl] = W2[kk * WN + c0 + tl];
        }
        __syncthreads();
        #pragma unroll
        for (int r = 0; r < 16; ++r) {
            int c = (r << 2) + th;
            W2T[(size_t)(c0 + c) * 64 + tl] = f2b(tile[tl][c]);
        }
    }
}

// ---------------------------------------------------------------------------
// Edge kernel: 1024 WGs x 256 threads (4 waves), 32 edges per WG.
// Proven-good combination: R4's fully-unrolled phase B (4 col-tiles/wave,
// all accumulators live, VGPR~128, NO spill) + R5's two-round reduction
// overlay (LDS 29.7KB). launch_bounds(256,2): do NOT force 4 waves/SIMD --
// the 128-budget forces a 64/64 arch/acc split and spills (R5-R8 evidence).
// If the allocator keeps <=128 VGPR we get 4 WG/CU and zero grid tail.
// ---------------------------------------------------------------------------
__global__ __launch_bounds__(256, 2) void edge_kernel(
    const float* __restrict__ h, const float* __restrict__ pos, const int* __restrict__ ei,
    const float* __restrict__ means, const float* __restrict__ betas,
    const float* __restrict__ W1, const float* __restrict__ b1,
    const u16* __restrict__ W2T, const float* __restrict__ b2,
    float* __restrict__ agg, float* __restrict__ cnt)
{
    // phase A layout:  sh_ss[32][33] @0 (4224) | sh_dot[32][17] @4224 (2176) |
    //   sh_v[32][68] @6400 (8704) | sh_cross[32][68] @15104 (8704) |
    //   sh_hidb @23808 (4608)  -> end 28416
    // reduction round 1: redS[4][32][33] @0 (16896) | redQ[4][32][17] @16896 (8704)
    // reduction round 2: redV[4][32][49] @0 (25088)
    __shared__ alignas(16) char sbuf[28416];
    float (*sh_ss)[33]    = (float (*)[33])(sbuf);
    float (*sh_dot)[17]   = (float (*)[17])(sbuf + 4224);
    float (*sh_v)[68]     = (float (*)[68])(sbuf + 6400);
    float (*sh_cross)[68] = (float (*)[68])(sbuf + 15104);
    u16*  sh_hidb         = (u16*)(sbuf + 23808);
    float (*redS)[32][33] = (float (*)[32][33])(sbuf);
    float (*redQ)[32][17] = (float (*)[32][17])(sbuf + 16896);
    float (*redV)[32][49] = (float (*)[32][49])(sbuf);

    __shared__ float sh_y1[32][3];
    __shared__ float sh_geo[32][2];
    __shared__ int   sh_src[32];
    __shared__ int   sh_dst[32];

    const int t = threadIdx.x;

    // ---- A1: per-edge geometry (threads 0..31) ----
    if (t < 32) {
        const int eg = (blockIdx.x << 5) + t;
        const int si = ei[eg];
        const int di = ei[EE + eg];
        float ax = pos[si*3+0], ay = pos[si*3+1], az = pos[si*3+2];
        float bx = pos[di*3+0], by = pos[di*3+1], bz = pos[di*3+2];
        float vx = bx-ax, vy = by-ay, vz = bz-az;
        float d = sqrtf(vx*vx + vy*vy + vz*vz + 1e-12f);
        float invd = 1.7320508075688772f / d;      // sqrt(3)/d
        sh_y1[t][0] = vx*invd; sh_y1[t][1] = vy*invd; sh_y1[t][2] = vz*invd;
        sh_geo[t][0] = expf(-d);                   // ALPHA = 1
        sh_geo[t][1] = (d < 5.0f) ? 0.5f*(cosf(d*0.6283185307179586f) + 1.0f) : 0.0f;
        sh_src[t] = si; sh_dst[t] = di;
    }
    __syncthreads();

    // ---- A2: rbf + hid(bf16) + pre-scaled coefficients (8 threads/edge) ----
    {
        const int e = t >> 3, r = t & 7;
        const float expd = sh_geo[e][0], cut = sh_geo[e][1];
        float rbf[16];
        #pragma unroll
        for (int k = 0; k < 16; ++k) {
            float td = expd - means[k];
            rbf[k] = expf(-betas[k]*td*td) * cut;
        }
        short8 pk;
        #pragma unroll
        for (int jj = 0; jj < 8; ++jj) {
            int j = (r << 3) + jj;
            float a = b1[j];
            #pragma unroll
            for (int k = 0; k < 16; ++k) a += rbf[k] * W1[(k<<6) + j];
            float s = a / (1.0f + expf(-a));        // silu
            pk[jj] = (short)f2b(s);
        }
        *(short8*)&sh_hidb[e*HID_STRIDE + (r<<3)] = pk;

        const int srcn = sh_src[e];
        const float* hrow = h + srcn*80;
        const float y1x = sh_y1[e][0], y1y = sh_y1[e][1], y1z = sh_y1[e][2];
        #pragma unroll
        for (int i = 0; i < 4; ++i) { int u = (r<<2)+i; sh_ss[e][u] = 0.125f * hrow[u]; }
        #pragma unroll
        for (int i = 0; i < 2; ++i) {
            int u = (r<<1)+i;
            float v0 = hrow[32+u*3+0];
            float v1 = hrow[32+u*3+1];
            float v2 = hrow[32+u*3+2];
            sh_v[e][(u<<2)+0] = v0 * 0.14433756729740643f;   // p3 scale folded
            sh_v[e][(u<<2)+1] = v1 * 0.14433756729740643f;
            sh_v[e][(u<<2)+2] = v2 * 0.14433756729740643f;
            sh_dot[e][u] = (v0*y1x + v1*y1y + v2*y1z) * 0.10206207261596574f; // /sqrt3 * p4
            sh_cross[e][(u<<2)+0] = (v1*y1z - v2*y1y) * 0.10206207261596574f; // /sqrt2 * p5
            sh_cross[e][(u<<2)+1] = (v2*y1x - v0*y1z) * 0.10206207261596574f;
            sh_cross[e][(u<<2)+2] = (v0*y1y - v1*y1x) * 0.10206207261596574f;
        }
    }
    __syncthreads();   // publish phase A

    // ---- A-fragments: hid rows (regs for all 160 col tiles) ----
    const int ln = t & 63, wv = t >> 6;
    const int quad = ln >> 4, lm = ln & 15;
    short8 af[2][2];   // [M-tile][K-step]; A[m=lm][k=ks*32+quad*8+j]
    #pragma unroll
    for (int mt = 0; mt < 2; ++mt)
        #pragma unroll
        for (int ks = 0; ks < 2; ++ks)
            af[mt][ks] = *(const short8*)&sh_hidb[(mt*16+lm)*HID_STRIDE + (ks<<5) + (quad<<3)];

    // ---- Phase B: 10 fully-unrolled chunks, register-resident contraction ----
    float accS[2][4][2];   // [mt][r][half]: out_s partial at (e, w=lm / lm+16)
    float accQ[2][4];      // q2 partial at (e, w=lm), scaled by 0.125
    float accV[2][4][3];   // (p3+p5) partial at (e, w=lm, d)
    #pragma unroll
    for (int mt = 0; mt < 2; ++mt)
        #pragma unroll
        for (int r = 0; r < 4; ++r) {
            accS[mt][r][0] = accS[mt][r][1] = 0.f;
            accQ[mt][r] = 0.f;
            accV[mt][r][0] = accV[mt][r][1] = accV[mt][r][2] = 0.f;
        }

    #pragma unroll
    for (int ci = 0; ci < 10; ++ci) {
        short8 bfr[4][2];
        float b2v[4];
        #pragma unroll
        for (int i = 0; i < 4; ++i) {
            const int coll = (((wv<<2)+i)<<4) + lm;
            const int col  = (ci<<8) + coll;
            bfr[i][0] = *(const short8*)(W2T + (size_t)col*64 + (quad<<3));
            bfr[i][1] = *(const short8*)(W2T + (size_t)col*64 + 32 + (quad<<3));
            b2v[i] = b2[col];
        }
        f32x4 d[4][2];
        #pragma unroll
        for (int i = 0; i < 4; ++i) {
            d[i][0] = (f32x4){0.f,0.f,0.f,0.f};
            d[i][1] = (f32x4){0.f,0.f,0.f,0.f};
            d[i][0] = __builtin_amdgcn_mfma_f32_16x16x32_bf16(af[0][0], bfr[i][0], d[i][0], 0,0,0);
            d[i][0] = __builtin_amdgcn_mfma_f32_16x16x32_bf16(af[0][1], bfr[i][1], d[i][0], 0,0,0);
            d[i][1] = __builtin_amdgcn_mfma_f32_16x16x32_bf16(af[1][0], bfr[i][0], d[i][1], 0,0,0);
            d[i][1] = __builtin_amdgcn_mfma_f32_16x16x32_bf16(af[1][1], bfr[i][1], d[i][1], 0,0,0);
            d[i][0] += b2v[i];     // ew = matmul + b2
            d[i][1] += b2v[i];
        }

        if (ci < 4) {                       // w_ss: j = ci*8 + {2wv, 2wv+1}, w halves
            const int ub = (ci<<3) + (wv<<1);
            #pragma unroll
            for (int mt = 0; mt < 2; ++mt)
                #pragma unroll
                for (int r = 0; r < 4; ++r) {
                    const int e = (mt<<4) + (quad<<2) + r;
                    float s0 = sh_ss[e][ub], s1 = sh_ss[e][ub+1];
                    accS[mt][r][0] += s0*d[0][mt][r] + s1*d[2][mt][r];
                    accS[mt][r][1] += s0*d[1][mt][r] + s1*d[3][mt][r];
                }
        } else if (ci < 6) {                // w_sv: w=lm, u=(ci-4)*16+4wv+i
            const int ub = ((ci-4)<<4) + (wv<<2);
            #pragma unroll
            for (int mt = 0; mt < 2; ++mt)
                #pragma unroll
                for (int r = 0; r < 4; ++r) {
                    const int e = (mt<<4) + (quad<<2) + r;
                    float a = 0.f;
                    #pragma unroll
                    for (int i = 0; i < 4; ++i) a += sh_ss[e][ub+i] * d[i][mt][r];
                    accQ[mt][r] += a;
                }
        } else if (ci == 6) {               // w_vs: w=lm, u=4wv+i
            const int ub = wv << 2;
            #pragma unroll
            for (int mt = 0; mt < 2; ++mt)
                #pragma unroll
                for (int r = 0; r < 4; ++r) {
                    const int e = (mt<<4) + (quad<<2) + r;
                    #pragma unroll
                    for (int i = 0; i < 4; ++i) {
                        const float4 vv = *(const float4*)&sh_v[e][(ub+i)<<2];
                        float ew = d[i][mt][r];
                        accV[mt][r][0] += vv.x * ew;
                        accV[mt][r][1] += vv.y * ew;
                        accV[mt][r][2] += vv.z * ew;
                    }
                }
        } else if (ci < 9) {                // w_vv0: like ss with dot (pre-scaled)
            const int ub = ((ci-7)<<3) + (wv<<1);
            #pragma unroll
            for (int mt = 0; mt < 2; ++mt)
                #pragma unroll
                for (int r = 0; r < 4; ++r) {
                    const int e = (mt<<4) + (quad<<2) + r;
                    float s0 = sh_dot[e][ub], s1 = sh_dot[e][ub+1];
                    accS[mt][r][0] += s0*d[0][mt][r] + s1*d[2][mt][r];
                    accS[mt][r][1] += s0*d[1][mt][r] + s1*d[3][mt][r];
                }
        } else {                            // w_vv1: like vs with cross (pre-scaled)
            const int ub = wv << 2;
            #pragma unroll
            for (int mt = 0; mt < 2; ++mt)
                #pragma unroll
                for (int r = 0; r < 4; ++r) {
                    const int e = (mt<<4) + (quad<<2) + r;
                    #pragma unroll
                    for (int i = 0; i < 4; ++i) {
                        const float4 cc = *(const float4*)&sh_cross[e][(ub+i)<<2];
                        float ew = d[i][mt][r];
                        accV[mt][r][0] += cc.x * ew;
                        accV[mt][r][1] += cc.y * ew;
                        accV[mt][r][2] += cc.z * ew;
                    }
                }
        }
    }

    // ---- reduction round 1: S + Q (overlay on dead phase-A arrays) ----
    __syncthreads();
    #pragma unroll
    for (int mt = 0; mt < 2; ++mt)
        #pragma unroll
        for (int r = 0; r < 4; ++r) {
            const int e = (mt<<4) + (quad<<2) + r;
            redS[wv][e][lm]    = accS[mt][r][0];
            redS[wv][e][lm+16] = accS[mt][r][1];
            redQ[wv][e][lm]    = accQ[mt][r];
        }
    __syncthreads();

    #pragma unroll
    for (int k = 0; k < 4; ++k) {
        int p = t + (k<<8); int e = p >> 5; int w = p & 31;
        float v = redS[0][e][w] + redS[1][e][w] + redS[2][e][w] + redS[3][e][w];
        atomicAdd(&agg[sh_dst[e]*80 + w], v);
    }
    float q2v[2];
    #pragma unroll
    for (int k = 0; k < 2; ++k) {
        int p = t + (k<<8); int e = p >> 4; int w = p & 15;
        q2v[k] = redQ[0][e][w] + redQ[1][e][w] + redQ[2][e][w] + redQ[3][e][w];
    }
    __syncthreads();   // redS/redQ consumed

    // ---- reduction round 2: V (same overlay region) ----
    #pragma unroll
    for (int mt = 0; mt < 2; ++mt)
        #pragma unroll
        for (int r = 0; r < 4; ++r) {
            const int e = (mt<<4) + (quad<<2) + r;
            redV[wv][e][lm*3+0] = accV[mt][r][0];
            redV[wv][e][lm*3+1] = accV[mt][r][1];
            redV[wv][e][lm*3+2] = accV[mt][r][2];
        }
    __syncthreads();

    #pragma unroll
    for (int k = 0; k < 2; ++k) {
        int p = t + (k<<8); int e = p >> 4; int w = p & 15;
        #pragma unroll
        for (int dd = 0; dd < 3; ++dd) {
            int m = w*3 + dd;
            float pv = redV[0][e][m] + redV[1][e][m] + redV[2][e][m] + redV[3][e][m];
            // q2 was accumulated with 0.125-scaled s; p2 term = q2/0.125*y1/sqrt(96)
            float val = pv + q2v[k] * sh_y1[e][dd] * 0.8164965809277261f;
            atomicAdd(&agg[sh_dst[e]*80 + 32 + m], val);
        }
    }
    if (t < 32) atomicAdd(&cnt[sh_dst[t]], 1.0f);
}

// ---------------------------------------------------------------------------
// Node kernel: out = agg/max(cnt,1) + self_interaction + h  (fp32 out).
// Block-uniform split: blocks [0,1024) scalar outputs, [1024,2560) vector.
// ---------------------------------------------------------------------------
__global__ __launch_bounds__(256, 8) void node_kernel(
    const float* __restrict__ h, const float* __restrict__ Wss, const float* __restrict__ Wvv,
    const float* __restrict__ agg, const float* __restrict__ cnt,
    float* __restrict__ out)
{
    const int b = blockIdx.x, t = threadIdx.x;
    if (b < 1024) {                         // scalar: NN*32 outputs
        const int idx = (b<<8) + t;
        const int n = idx >> 5, j = idx & 31;
        const float* hrow = h + n*80;
        float si = 0.f;
        #pragma unroll
        for (int u = 0; u < 32; ++u) si += hrow[u] * Wss[(u<<5)+j];
        float a = agg[n*80+j] / fmaxf(cnt[n], 1.0f);
        out[n*80+j] = a + si*0.17677669529663687f + hrow[j];   // 1/sqrt(32)
    } else {                                // vector: NN*48 outputs
        const int idx = ((b-1024)<<8) + t;
        const int n = idx / 48, m = idx - n*48;
        const int w = m/3, d = m - w*3;
        const float* hrow = h + n*80;
        float si = 0.f;
        #pragma unroll
        for (int u = 0; u < 16; ++u) si += hrow[32+u*3+d] * Wvv[(u<<4)+w];
        float a = agg[n*80+32+m] / fmaxf(cnt[n], 1.0f);
        out[n*80+32+m] = a + si*0.25f + hrow[32+m];            // 1/sqrt(16)
    }
}

extern "C" void kernel_launch(void* const* d_in, const int* in_sizes, int n_in,
                              void* d_out, int out_size, void* d_ws, size_t ws_size,
                              hipStream_t stream) {
    const float* h     = (const float*)d_in[0];
    const float* pos   = (const float*)d_in[1];
    const int*   ei    = (const int*)d_in[2];
    const float* means = (const float*)d_in[3];
    const float* betas = (const float*)d_in[4];
    const float* W1    = (const float*)d_in[5];
    const float* b1    = (const float*)d_in[6];
    const float* W2    = (const float*)d_in[7];
    const float* b2    = (const float*)d_in[8];
    const float* Wss   = (const float*)d_in[9];
    const float* Wvv   = (const float*)d_in[10];

    float* agg = (float*)d_ws;
    float* cnt = agg + (size_t)NN*80;
    u16*   W2T = (u16*)(cnt + NN);          // 2560*64 bf16 = 320 KB

    hipLaunchKernelGGL(prep, dim3(256), dim3(256), 0, stream, W2, W2T, agg);
    hipLaunchKernelGGL(edge_kernel, dim3(EE/32), dim3(256), 0, stream,
                       h, pos, ei, means, betas, W1, b1, W2T, b2, agg, cnt);
    hipLaunchKernelGGL(node_kernel, dim3(2560), dim3(256), 0, stream,
                       h, Wss, Wvv, agg, cnt, (float*)d_out);
}